// Round 2
// baseline (25204.587 us; speedup 1.0000x reference)
//
#include <hip/hip_runtime.h>
#include <hip/hip_bf16.h>

// ---------------------------------------------------------------------------
// RNNModel (MDN-RNN): embed+concat -> x_pre -> 511-step LSTM -> out GEMM ->
// logsumexp heads.
// Decomposition:
//   cvt_wout_k : W_out fp32 -> bf16 (row-major [1921][1024], direct B-frag)
//   cvt_z_k    : z [B][T][128] fp32 -> zt [T][B][128] bf16
//   lstm_k     : persistent, 256 blocks (1/CU). Block j owns h[4j..4j+4) i.e.
//                16 gate rows (i,f,g,o x 4). W_hh slice bf16-swizzled in LDS.
//                Per step: MFMA (M=32 batches, N=16 gates, K=1024+128),
//                fp32 c-state in regs, global counter barrier, dbl-buffered h.
//   out_gemm_k : hs[16352][1024]bf16 @ W_out^T, tile 64x80 (80 = 16 groups of
//                5 -> logsumexp never crosses a tile), fused bias+lse epilogue.
//   donep_k    : last output column (done logit), wave-per-row dot.
// Round-1 fix: out_gemm_k B-stage filled only 64/128 elements per LDS row
// (i<640, n=i>>3) -> MFMA read uninitialized LDS -> NaN. Now 1280 chunks.
// Also zero hs padding rows (16352..16383) read by the last M-tile.
// ---------------------------------------------------------------------------

typedef float f4 __attribute__((ext_vector_type(4)));
typedef short s8 __attribute__((ext_vector_type(8)));
typedef unsigned short us8v __attribute__((ext_vector_type(8)));
typedef unsigned short us4v __attribute__((ext_vector_type(4)));

#define DEV __device__ __forceinline__

DEV unsigned short f2b(float f) {          // fp32 -> bf16 RNE
  unsigned u = __float_as_uint(f);
  return (unsigned short)((u + 0x7FFFu + ((u >> 16) & 1u)) >> 16);
}
DEV float b2f(unsigned short s) { return __uint_as_float(((unsigned)s) << 16); }

DEV f4 MFMA(s8 a, s8 b, f4 c) {
  return __builtin_amdgcn_mfma_f32_16x16x32_bf16(a, b, c, 0, 0, 0);
}
DEV s8 LD8(const unsigned short* p) { return *reinterpret_cast<const s8*>(p); }

// ---- workspace layout (bytes) ----
static constexpr size_t WS_HBUF = 128;
static constexpr size_t WS_ZT   = 131328;
static constexpr size_t WS_WOUT = 4325632;
static constexpr size_t WS_HS   = 8259840;
static constexpr size_t WS_END  = 41814272;

// ---------------------------------------------------------------------------
__global__ void cvt_wout_k(const float* __restrict__ W, unsigned short* __restrict__ o) {
  int i = blockIdx.x * 256 + threadIdx.x;         // 491776 float4 units exact
  if (i < 491776) {
    const float4 v = reinterpret_cast<const float4*>(W)[i];
    us4v u; u[0] = f2b(v.x); u[1] = f2b(v.y); u[2] = f2b(v.z); u[3] = f2b(v.w);
    reinterpret_cast<us4v*>(o)[i] = u;
  }
}

__global__ void cvt_z_k(const float* __restrict__ z, unsigned short* __restrict__ zt) {
  int u = blockIdx.x * 256 + threadIdx.x;         // 524288 units exact
  if (u < 524288) {
    int d4 = u & 31, bt = u >> 5;
    int b = bt & 31, t = bt >> 5;
    const float4 v = reinterpret_cast<const float4*>(z)[(b * 512 + t) * 32 + d4];
    us4v uu; uu[0] = f2b(v.x); uu[1] = f2b(v.y); uu[2] = f2b(v.z); uu[3] = f2b(v.w);
    reinterpret_cast<us4v*>(zt)[u] = uu;
  }
}

__global__ void zero_hs_tail_k(unsigned short* __restrict__ hs) {
  // rows 16352..16383 (32 rows x 1024 bf16) -> 8192 us4 units
  int i = blockIdx.x * 256 + threadIdx.x;
  if (i < 16384) {
    us4v zz = {0, 0, 0, 0};
    reinterpret_cast<us4v*>(hs + (size_t)16352 * 1024)[i] = zz;
  }
}

// ---------------------------------------------------------------------------
// Persistent LSTM. grid=256, block=256 (4 waves). One block per CU.
// Wave w handles K-slice [w*256,(w+1)*256) of W_hh plus z-K [w*32,(w+1)*32);
// partial D reduced across waves via LDS.
__global__ __launch_bounds__(256, 1) void lstm_k(
    const float* __restrict__ Whh, const float* __restrict__ Wih,
    const float* __restrict__ embed, const float* __restrict__ bih,
    const float* __restrict__ bhh, const int* __restrict__ actions,
    const int* __restrict__ dones, const unsigned short* __restrict__ zt,
    unsigned short* __restrict__ h_buf, unsigned short* __restrict__ hs,
    unsigned* __restrict__ cnt) {
  const int blk = blockIdx.x;
  const int tid = threadIdx.x;
  const int lane = tid & 63;
  const int w = tid >> 6;
  const int ln = lane & 15, lk = lane >> 4;

  __shared__ alignas(16) unsigned short whh_sw[32 * 64 * 8];   // 32 KB
  __shared__ alignas(16) unsigned short wz_sw[4 * 64 * 8];     // 4 KB
  __shared__ float abias[18][16];   // per-action gate bias (embed part + b_ih + b_hh)
  __shared__ float red[4][32][20];  // per-wave partial D [wave][batch][gate]

  for (int i = tid; i < 32 * 64 * 8; i += 256) {
    int j = i & 7, L = (i >> 3) & 63, kt = i >> 9;
    int n = L & 15;
    int grow = (n >> 2) * 1024 + blk * 4 + (n & 3);
    int k = kt * 32 + ((L >> 4) << 3) + j;
    whh_sw[i] = f2b(Whh[grow * 1024 + k]);
  }
  for (int i = tid; i < 4 * 64 * 8; i += 256) {
    int j = i & 7, L = (i >> 3) & 63, kt = i >> 9;
    int n = L & 15;
    int grow = (n >> 2) * 1024 + blk * 4 + (n & 3);
    int k = kt * 32 + ((L >> 4) << 3) + j;
    wz_sw[i] = f2b(Wih[grow * 144 + k]);
  }
  for (int i = tid; i < 18 * 16; i += 256) {
    int a = i >> 4, n = i & 15;
    int grow = (n >> 2) * 1024 + blk * 4 + (n & 3);
    float s = bih[grow] + bhh[grow];
    for (int j = 0; j < 16; ++j) s += embed[a * 16 + j] * Wih[grow * 144 + 128 + j];
    abias[a][n] = s;
  }
  __syncthreads();

  const int eb = tid & 31, eq = tid >> 5;   // epilogue mapping (tid < 128)
  float c_state = 0.f;
  unsigned target = 0;

  for (int t = 0; t < 511; ++t) {
    const int p = t & 1;
    const unsigned short* hb = h_buf + p * 32768;

    f4 acc0 = {0.f, 0.f, 0.f, 0.f};
    f4 acc1 = {0.f, 0.f, 0.f, 0.f};

    {  // z contribution first: independent of h -> overlaps barrier wait
      const unsigned short* zb = zt + (size_t)t * 4096;
      const int kz = w * 32 + (lk << 3);
      s8 a0 = LD8(zb + ln * 128 + kz);
      s8 a1 = LD8(zb + (ln + 16) * 128 + kz);
      s8 bf = LD8(wz_sw + ((w * 64 + lane) << 3));
      acc0 = MFMA(a0, bf, acc0);
      acc1 = MFMA(a1, bf, acc1);
    }

    if (t) {  // wait until all 256 blocks finished step t-1
      if (tid == 0) {
        unsigned spin = 0;
        while (__hip_atomic_load(cnt, __ATOMIC_RELAXED, __HIP_MEMORY_SCOPE_AGENT) < target &&
               spin < (1u << 22)) {
          __builtin_amdgcn_s_sleep(2);
          ++spin;
        }
      }
      __syncthreads();
      __threadfence();  // acquire: invalidate stale h lines (cross-XCD)
    }

#pragma unroll
    for (int kk = 0; kk < 8; ++kk) {   // this wave's 8 K-steps of W_hh
      const int kt = w * 8 + kk;
      const int k0 = kt * 32 + (lk << 3);
      s8 a0 = LD8(hb + ln * 1024 + k0);
      s8 a1 = LD8(hb + (ln + 16) * 1024 + k0);
      s8 bf = LD8(whh_sw + ((kt * 64 + lane) << 3));
      acc0 = MFMA(a0, bf, acc0);
      acc1 = MFMA(a1, bf, acc1);
    }

    // D layout: row(batch) = 4*(lane>>4)+j, col(gate) = lane&15
#pragma unroll
    for (int j = 0; j < 4; ++j) {
      red[w][(lk << 2) + j][ln] = acc0[j];
      red[w][16 + (lk << 2) + j][ln] = acc1[j];
    }
    __syncthreads();

    if (tid < 128) {  // one thread per (batch eb, local h-index eq)
      float gi = 0.f, gf = 0.f, gg = 0.f, go = 0.f;
#pragma unroll
      for (int ww = 0; ww < 4; ++ww) {
        gi += red[ww][eb][eq];
        gf += red[ww][eb][4 + eq];
        gg += red[ww][eb][8 + eq];
        go += red[ww][eb][12 + eq];
      }
      const int a = actions[eb * 512 + t];
      gi += abias[a][eq];       gf += abias[a][4 + eq];
      gg += abias[a][8 + eq];   go += abias[a][12 + eq];
      const float si = 1.f / (1.f + expf(-gi));
      const float sf = 1.f / (1.f + expf(-gf));
      const float so = 1.f / (1.f + expf(-go));
      const float cn = sf * c_state + si * tanhf(gg);
      const float hn = so * tanhf(cn);
      const float m = 1.f - (float)dones[eb * 512 + t];
      c_state = cn * m;                                   // fp32 carry
      h_buf[(1 - p) * 32768 + eb * 1024 + blk * 4 + eq] = f2b(hn * m);  // masked carry
      hs[(size_t)(eb * 511 + t) * 1024 + blk * 4 + eq] = f2b(hn);       // unmasked output
    }
    __threadfence();   // release: drain stores + L2 writeback before arrival
    __syncthreads();
    if (tid == 0) atomicAdd(cnt, 1u);
    target += 256;
  }
}

// ---------------------------------------------------------------------------
// out = hs @ W_out^T (+bias), fused logsumexp on the logmix third.
// grid = (256 Mblk of 64 rows, 24 Nblk of 80 cols). Wave w -> rows [w*16,+16).
__global__ __launch_bounds__(256, 2) void out_gemm_k(
    const unsigned short* __restrict__ hs, const unsigned short* __restrict__ wout,
    const float* __restrict__ b_out, float* __restrict__ out) {
  const int mblk = blockIdx.x, nblk = blockIdx.y;
  const int tid = threadIdx.x, lane = tid & 63, w = tid >> 6;
  const int ln = lane & 15, lk = lane >> 4;
  __shared__ alignas(16) unsigned char smraw[21760];
  unsigned short* bsm = (unsigned short*)smraw;  // [80][136] bf16 B-chunk
  float* ep = (float*)smraw;                     // [64][84] f32 epilogue tile

  const int r0 = mblk * 64 + w * 16;
  f4 acc[5];
#pragma unroll
  for (int s = 0; s < 5; ++s) acc[s] = (f4){0.f, 0.f, 0.f, 0.f};

  for (int kc = 0; kc < 8; ++kc) {  // K chunks of 128
    // 80 rows x 128 bf16 = 1280 us8 chunks = 5 x 256 threads (exact)
#pragma unroll
    for (int ii = 0; ii < 5; ++ii) {
      int i = tid + ii * 256;
      int n = i >> 4, k16 = i & 15;
      us8v v = *reinterpret_cast<const us8v*>(
          wout + (size_t)(nblk * 80 + n) * 1024 + kc * 128 + (k16 << 3));
      *reinterpret_cast<us8v*>(bsm + n * 136 + (k16 << 3)) = v;
    }
    __syncthreads();
#pragma unroll
    for (int ks = 0; ks < 4; ++ks) {
      const int k0 = kc * 128 + ks * 32 + (lk << 3);
      s8 a = LD8(hs + (size_t)(r0 + ln) * 1024 + k0);
#pragma unroll
      for (int s = 0; s < 5; ++s) {
        s8 b = LD8(bsm + (s * 16 + ln) * 136 + ks * 32 + (lk << 3));
        acc[s] = MFMA(a, b, acc[s]);
      }
    }
    __syncthreads();
  }

  const int T = nblk >> 3;  // 0 logmix, 1 mu, 2 logstd
  if (T) {
    float* base = out + (size_t)10465280 * T;
    const int lc0 = (nblk - (T << 3)) * 80;
#pragma unroll
    for (int s = 0; s < 5; ++s) {
      const int lc = lc0 + s * 16 + ln;
      const float bias = b_out[T * 640 + lc];
#pragma unroll
      for (int j = 0; j < 4; ++j) {
        const int row = r0 + (lk << 2) + j;
        if (row < 16352) base[(size_t)row * 640 + lc] = acc[s][j] + bias;
      }
    }
  } else {  // logmix: bounce through LDS, per-(row, z-group) logsumexp over 5
#pragma unroll
    for (int s = 0; s < 5; ++s) {
      const float bias = b_out[nblk * 80 + s * 16 + ln];
#pragma unroll
      for (int j = 0; j < 4; ++j)
        ep[(w * 16 + (lk << 2) + j) * 84 + s * 16 + ln] = acc[s][j] + bias;
    }
    __syncthreads();
    for (int task = tid; task < 1024; task += 256) {
      const int rr = task >> 4, grp = task & 15;
      const int row = mblk * 64 + rr;
      const float* e = ep + rr * 84 + grp * 5;
      float v0 = e[0], v1 = e[1], v2 = e[2], v3 = e[3], v4 = e[4];
      float mx = fmaxf(fmaxf(fmaxf(v0, v1), fmaxf(v2, v3)), v4);
      float ssum = expf(v0 - mx) + expf(v1 - mx) + expf(v2 - mx) +
                   expf(v3 - mx) + expf(v4 - mx);
      float lse = mx + logf(ssum);
      if (row < 16352) {
        float* o = out + (size_t)row * 640 + nblk * 80 + grp * 5;
        o[0] = v0 - lse; o[1] = v1 - lse; o[2] = v2 - lse;
        o[3] = v3 - lse; o[4] = v4 - lse;
      }
    }
  }
}

// ---------------------------------------------------------------------------
__global__ __launch_bounds__(256) void donep_k(
    const unsigned short* __restrict__ hs, const unsigned short* __restrict__ wout,
    const float* __restrict__ b_out, float* __restrict__ out) {
  const int lane = threadIdx.x & 63;
  const int wv = (blockIdx.x * 256 + threadIdx.x) >> 6;  // 2048 waves
  const unsigned short* wrow = wout + (size_t)1920 * 1024 + lane * 16;
  float wl[16];
#pragma unroll
  for (int i = 0; i < 16; ++i) wl[i] = b2f(wrow[i]);
  const float bias = b_out[1920];
  for (int r = wv; r < 16352; r += 2048) {
    const unsigned short* hr = hs + (size_t)r * 1024 + lane * 16;
    float d = 0.f;
#pragma unroll
    for (int i = 0; i < 16; ++i) d += b2f(hr[i]) * wl[i];
#pragma unroll
    for (int off = 32; off; off >>= 1) d += __shfl_down(d, off, 64);
    if (lane == 0) out[31395840 + r] = d + bias;
  }
}

// ---------------------------------------------------------------------------
extern "C" void kernel_launch(void* const* d_in, const int* in_sizes, int n_in,
                              void* d_out, int out_size, void* d_ws, size_t ws_size,
                              hipStream_t stream) {
  const float* z       = (const float*)d_in[0];
  const int*   actions = (const int*)d_in[1];
  const int*   dones   = (const int*)d_in[2];
  const float* embed   = (const float*)d_in[3];
  const float* Wih     = (const float*)d_in[4];
  const float* Whh     = (const float*)d_in[5];
  const float* bih     = (const float*)d_in[6];
  const float* bhh     = (const float*)d_in[7];
  const float* Wout    = (const float*)d_in[8];
  const float* bout    = (const float*)d_in[9];
  float* out = (float*)d_out;

  if (ws_size < WS_END) return;  // fail visibly rather than corrupt memory

  char* ws = (char*)d_ws;
  unsigned* cnt          = (unsigned*)(ws);
  unsigned short* h_buf  = (unsigned short*)(ws + WS_HBUF);
  unsigned short* zt     = (unsigned short*)(ws + WS_ZT);
  unsigned short* wout16 = (unsigned short*)(ws + WS_WOUT);
  unsigned short* hs     = (unsigned short*)(ws + WS_HS);

  // zero barrier counter + initial h (h0 = 0); must happen every launch
  hipMemsetAsync(d_ws, 0, 131200, stream);

  cvt_wout_k<<<1921, 256, 0, stream>>>(Wout, wout16);
  cvt_z_k<<<2048, 256, 0, stream>>>(z, zt);
  zero_hs_tail_k<<<64, 256, 0, stream>>>(hs);
  lstm_k<<<256, 256, 0, stream>>>(Whh, Wih, embed, bih, bhh, actions, dones,
                                  zt, h_buf, hs, cnt);
  out_gemm_k<<<dim3(256, 24), 256, 0, stream>>>(hs, wout16, bout, out);
  donep_k<<<512, 256, 0, stream>>>(hs, wout16, bout, out);
}

// Round 4
// 2995.826 us; speedup vs baseline: 8.4132x; 8.4132x over previous
//
#include <hip/hip_runtime.h>
#include <hip/hip_bf16.h>

// ---------------------------------------------------------------------------
// RNNModel (MDN-RNN): embed+concat -> x_pre -> 511-step LSTM -> out GEMM ->
// logsumexp heads.
//   lstm_k: persistent 256 blocks (1/CU), W_hh bf16 in LDS. Per step:
//     MFMA [32 x 16gates x K1152], fp32 c in regs.
//     Cross-block h exchange: 8B agent-scope relaxed atomics (LLC-coherent)
//     -- NO __threadfence (round-2: full per-L2 writeback/inv = 49.6us/step).
//     Arrival = s_waitcnt vmcnt(0) + relaxed atomicAdd on 16 group counters.
//   h64 carry layout [phase][batch][256 u64]: ROUND-3 BUG WAS STRIDE 128
//     (H=1024 bf16 = 256 u64/row) -> two blocks aliased every index, race on
//     31/32 of h. Fixed: phase offset 8192, writer tid*256+blk, reader ln*256.
//   hs2: block-major [kgroup=blk][row(b,t)][4cols] u64 -- per-block
//     contiguous 128KB, single-XCD-L2 dirty lines (kills 8x write amp).
//   out_gemm_k: 64x80 tiles (80 = 16 groups of 5 -> lse intra-tile),
//     A-frags = 2x8B from hs2. donep_k: 4x8B per lane.
// ---------------------------------------------------------------------------

typedef float f4 __attribute__((ext_vector_type(4)));
typedef short s8 __attribute__((ext_vector_type(8)));
typedef unsigned short us8v __attribute__((ext_vector_type(8)));
typedef unsigned short us4v __attribute__((ext_vector_type(4)));
typedef unsigned long long u64;

#define DEV __device__ __forceinline__

DEV unsigned short f2b(float f) {          // fp32 -> bf16 RNE
  unsigned u = __float_as_uint(f);
  return (unsigned short)((u + 0x7FFFu + ((u >> 16) & 1u)) >> 16);
}
DEV float b2f(unsigned short s) { return __uint_as_float(((unsigned)s) << 16); }

DEV f4 MFMA(s8 a, s8 b, f4 c) {
  return __builtin_amdgcn_mfma_f32_16x16x32_bf16(a, b, c, 0, 0, 0);
}
DEV s8 LD8(const unsigned short* p) { return *reinterpret_cast<const s8*>(p); }

DEV s8 LDH(const u64* p) {  // 16B of h via 2 coherent (LLC) 8B atomic loads
  union { u64 q[2]; s8 v; } u;
  u.q[0] = __hip_atomic_load(p, __ATOMIC_RELAXED, __HIP_MEMORY_SCOPE_AGENT);
  u.q[1] = __hip_atomic_load(p + 1, __ATOMIC_RELAXED, __HIP_MEMORY_SCOPE_AGENT);
  return u.v;
}

// ---- workspace layout (bytes) ----
// [0,2048)    16 barrier group counters, 128B apart
// [2048, +131072)   h64: 2 x 32 x 256 u64 (dbl-buffered carry h, bf16 packed)
// [133120, +4MiB)   zt : 512 x 32 x 128 bf16
// [4327424, +3.75MiB) wout16
// [8261632, +32MiB) hs2: 256 kgroups x 16384 rows x u64
static constexpr size_t WS_HBUF = 2048;
static constexpr size_t WS_ZT   = 133120;
static constexpr size_t WS_WOUT = 4327424;
static constexpr size_t WS_HS2  = 8261632;
static constexpr size_t WS_END  = 41816064;

// ---------------------------------------------------------------------------
__global__ void cvt_wout_k(const float* __restrict__ W, unsigned short* __restrict__ o) {
  int i = blockIdx.x * 256 + threadIdx.x;         // 491776 float4 units exact
  if (i < 491776) {
    const float4 v = reinterpret_cast<const float4*>(W)[i];
    us4v u; u[0] = f2b(v.x); u[1] = f2b(v.y); u[2] = f2b(v.z); u[3] = f2b(v.w);
    reinterpret_cast<us4v*>(o)[i] = u;
  }
}

__global__ void cvt_z_k(const float* __restrict__ z, unsigned short* __restrict__ zt) {
  int u = blockIdx.x * 256 + threadIdx.x;         // 524288 units exact
  if (u < 524288) {
    int d4 = u & 31, bt = u >> 5;
    int b = bt & 31, t = bt >> 5;
    const float4 v = reinterpret_cast<const float4*>(z)[(b * 512 + t) * 32 + d4];
    us4v uu; uu[0] = f2b(v.x); uu[1] = f2b(v.y); uu[2] = f2b(v.z); uu[3] = f2b(v.w);
    reinterpret_cast<us4v*>(zt)[u] = uu;
  }
}

__global__ void zero_hs_tail_k(u64* __restrict__ hs2) {
  // rows 16352..16383 of all 256 kgroup regions
  int i = blockIdx.x * 256 + threadIdx.x;
  if (i < 8192) {
    int region = i >> 5, r = 16352 + (i & 31);
    hs2[(size_t)region * 16384 + r] = 0ull;
  }
}

// ---------------------------------------------------------------------------
// Persistent LSTM. grid=256, block=256 (4 waves). Block blk owns h cols
// [4blk,4blk+4) = gate rows {g*1024+4blk+q}. Wave w owns K-slice
// [256w,256w+256) + z-K [32w,+32). 511 steps, hierarchical LLC barrier.
__global__ __launch_bounds__(256, 1) void lstm_k(
    const float* __restrict__ Whh, const float* __restrict__ Wih,
    const float* __restrict__ embed, const float* __restrict__ bih,
    const float* __restrict__ bhh, const int* __restrict__ actions,
    const int* __restrict__ dones, const unsigned short* __restrict__ zt,
    u64* __restrict__ h64, u64* __restrict__ hs2,
    unsigned* __restrict__ gcnt) {
  const int blk = blockIdx.x;
  const int tid = threadIdx.x;
  const int lane = tid & 63;
  const int w = tid >> 6;
  const int ln = lane & 15, lk = lane >> 4;

  __shared__ alignas(16) unsigned short whh_sw[32 * 64 * 8];   // 32 KB
  __shared__ alignas(16) unsigned short wz_sw[4 * 64 * 8];     // 4 KB
  __shared__ float abias[18][16];
  __shared__ float red[4][32][21];     // padded 21: conflict-free reads
  __shared__ alignas(8) unsigned short st[2][32][4];  // packed h staging

  for (int i = tid; i < 32 * 64 * 8; i += 256) {
    int j = i & 7, L = (i >> 3) & 63, kt = i >> 9;
    int n = L & 15;
    int grow = (n >> 2) * 1024 + blk * 4 + (n & 3);
    int k = kt * 32 + ((L >> 4) << 3) + j;
    whh_sw[i] = f2b(Whh[grow * 1024 + k]);
  }
  for (int i = tid; i < 4 * 64 * 8; i += 256) {
    int j = i & 7, L = (i >> 3) & 63, kt = i >> 9;
    int n = L & 15;
    int grow = (n >> 2) * 1024 + blk * 4 + (n & 3);
    int k = kt * 32 + ((L >> 4) << 3) + j;
    wz_sw[i] = f2b(Wih[grow * 144 + k]);
  }
  for (int i = tid; i < 18 * 16; i += 256) {
    int a = i >> 4, n = i & 15;
    int grow = (n >> 2) * 1024 + blk * 4 + (n & 3);
    float s = bih[grow] + bhh[grow];
    for (int j = 0; j < 16; ++j) s += embed[a * 16 + j] * Wih[grow * 144 + 128 + j];
    abias[a][n] = s;
  }
  __syncthreads();

  const int eb = tid & 31, eq = tid >> 5;   // epilogue mapping (tid < 128)
  float c_state = 0.f;

  for (int t = 0; t < 511; ++t) {
    const int p = t & 1;
    const u64* hb = h64 + p * 8192;          // 32 rows x 256 u64

    f4 acc0 = {0.f, 0.f, 0.f, 0.f};
    f4 acc1 = {0.f, 0.f, 0.f, 0.f};

    {  // z contribution: independent of h -> overlaps barrier wait
      const unsigned short* zb = zt + (size_t)t * 4096;
      const int kz = w * 32 + (lk << 3);
      s8 a0 = LD8(zb + ln * 128 + kz);
      s8 a1 = LD8(zb + (ln + 16) * 128 + kz);
      s8 bf = LD8(wz_sw + ((w * 64 + lane) << 3));
      acc0 = MFMA(a0, bf, acc0);
      acc1 = MFMA(a1, bf, acc1);
    }
    // per-step scalars: independent of h, issue before the spin
    int a_t = 0; float m_t = 0.f;
    if (tid < 128) {
      a_t = actions[eb * 512 + t];
      m_t = 1.f - (float)dones[eb * 512 + t];
    }

    if (t) {  // wait for step t-1: all 16 group counters reach 16*t
      if (tid == 0) {
        const unsigned tgt = (unsigned)t * 16u;
        for (unsigned spin = 0; spin < (1u << 20); ++spin) {
          unsigned mn = 0xFFFFFFFFu;
#pragma unroll
          for (int g = 0; g < 16; ++g) {
            unsigned v = __hip_atomic_load(gcnt + g * 32, __ATOMIC_RELAXED,
                                           __HIP_MEMORY_SCOPE_AGENT);
            mn = (v < mn) ? v : mn;
          }
          if (mn >= tgt) break;
          __builtin_amdgcn_s_sleep(1);
        }
      }
      __syncthreads();
    }

#pragma unroll
    for (int kk = 0; kk < 8; ++kk) {   // this wave's 8 K-steps of W_hh
      const int kt = w * 8 + kk;
      s8 a0 = LDH(hb + ln * 256 + kt * 8 + (lk << 1));
      s8 a1 = LDH(hb + (ln + 16) * 256 + kt * 8 + (lk << 1));
      s8 bf = LD8(whh_sw + ((kt * 64 + lane) << 3));
      acc0 = MFMA(a0, bf, acc0);
      acc1 = MFMA(a1, bf, acc1);
    }

    // D layout: row(batch) = 4*(lane>>4)+j, col(gate) = lane&15
#pragma unroll
    for (int j = 0; j < 4; ++j) {
      red[w][(lk << 2) + j][ln] = acc0[j];
      red[w][16 + (lk << 2) + j][ln] = acc1[j];
    }
    __syncthreads();

    if (tid < 128) {  // one thread per (batch eb, local h-index eq)
      float gi = 0.f, gf = 0.f, gg = 0.f, go = 0.f;
#pragma unroll
      for (int ww = 0; ww < 4; ++ww) {
        gi += red[ww][eb][eq];
        gf += red[ww][eb][4 + eq];
        gg += red[ww][eb][8 + eq];
        go += red[ww][eb][12 + eq];
      }
      gi += abias[a_t][eq];       gf += abias[a_t][4 + eq];
      gg += abias[a_t][8 + eq];   go += abias[a_t][12 + eq];
      const float si = 1.f / (1.f + expf(-gi));
      const float sf = 1.f / (1.f + expf(-gf));
      const float so = 1.f / (1.f + expf(-go));
      const float cn = sf * c_state + si * tanhf(gg);
      const float hn = so * tanhf(cn);
      c_state = cn * m_t;                      // fp32 carry
      st[0][eb][eq] = f2b(hn);                 // unmasked -> hs2
      st[1][eb][eq] = f2b(hn * m_t);           // masked   -> carry h
    }
    __syncthreads();

    if (tid < 32) {  // pack 4 cols -> one 8B store each
      const u64 hu  = *reinterpret_cast<const u64*>(&st[0][tid][0]);
      const u64 hum = *reinterpret_cast<const u64*>(&st[1][tid][0]);
      hs2[(size_t)blk * 16384 + tid * 511 + t] = hu;           // plain, own-L2
      __hip_atomic_store(h64 + (1 - p) * 8192 + tid * 256 + blk, hum,
                         __ATOMIC_RELAXED, __HIP_MEMORY_SCOPE_AGENT);
    }
    if (tid == 0) {  // arrival: drain wave-0 stores to LLC, then group add
      asm volatile("s_waitcnt vmcnt(0)" ::: "memory");
      __hip_atomic_fetch_add(gcnt + (blk >> 4) * 32, 1u,
                             __ATOMIC_RELAXED, __HIP_MEMORY_SCOPE_AGENT);
    }
  }
}

// ---------------------------------------------------------------------------
// out = hs @ W_out^T (+bias), fused logsumexp on the logmix third.
// grid = (256 Mblk of 64 rows, 24 Nblk of 80 cols). Wave w -> rows [w*16,+16).
__global__ __launch_bounds__(256, 2) void out_gemm_k(
    const u64* __restrict__ hs2, const unsigned short* __restrict__ wout,
    const float* __restrict__ b_out, float* __restrict__ out) {
  const int mblk = blockIdx.x, nblk = blockIdx.y;
  const int tid = threadIdx.x, lane = tid & 63, w = tid >> 6;
  const int ln = lane & 15, lk = lane >> 4;
  __shared__ alignas(16) unsigned char smraw[21760];
  unsigned short* bsm = (unsigned short*)smraw;  // [80][136] bf16 B-chunk
  float* ep = (float*)smraw;                     // [64][84] f32 epilogue tile

  const int r0 = mblk * 64 + w * 16;
  f4 acc[5];
#pragma unroll
  for (int s = 0; s < 5; ++s) acc[s] = (f4){0.f, 0.f, 0.f, 0.f};

  for (int kc = 0; kc < 8; ++kc) {  // K chunks of 128
#pragma unroll
    for (int ii = 0; ii < 5; ++ii) {           // 1280 us8 chunks exact
      int i = tid + ii * 256;
      int n = i >> 4, k16 = i & 15;
      us8v v = *reinterpret_cast<const us8v*>(
          wout + (size_t)(nblk * 80 + n) * 1024 + kc * 128 + (k16 << 3));
      *reinterpret_cast<us8v*>(bsm + n * 136 + (k16 << 3)) = v;
    }
    __syncthreads();
#pragma unroll
    for (int ks = 0; ks < 4; ++ks) {
      const int k0 = kc * 128 + ks * 32 + (lk << 3);
      union { u64 q[2]; s8 v; } ua;            // A-frag: 2 x 8B from hs2
      ua.q[0] = hs2[(size_t)(k0 >> 2) * 16384 + r0 + ln];
      ua.q[1] = hs2[((size_t)(k0 >> 2) + 1) * 16384 + r0 + ln];
#pragma unroll
      for (int s = 0; s < 5; ++s) {
        s8 b = LD8(bsm + (s * 16 + ln) * 136 + ks * 32 + (lk << 3));
        acc[s] = MFMA(ua.v, b, acc[s]);
      }
    }
    __syncthreads();
  }

  const int T = nblk >> 3;  // 0 logmix, 1 mu, 2 logstd
  if (T) {
    float* base = out + (size_t)10465280 * T;
    const int lc0 = (nblk - (T << 3)) * 80;
#pragma unroll
    for (int s = 0; s < 5; ++s) {
      const int lc = lc0 + s * 16 + ln;
      const float bias = b_out[T * 640 + lc];
#pragma unroll
      for (int j = 0; j < 4; ++j) {
        const int row = r0 + (lk << 2) + j;
        if (row < 16352) base[(size_t)row * 640 + lc] = acc[s][j] + bias;
      }
    }
  } else {  // logmix: bounce through LDS, per-(row, z-group) logsumexp over 5
#pragma unroll
    for (int s = 0; s < 5; ++s) {
      const float bias = b_out[nblk * 80 + s * 16 + ln];
#pragma unroll
      for (int j = 0; j < 4; ++j)
        ep[(w * 16 + (lk << 2) + j) * 84 + s * 16 + ln] = acc[s][j] + bias;
    }
    __syncthreads();
    for (int task = tid; task < 1024; task += 256) {
      const int rr = task >> 4, grp = task & 15;
      const int row = mblk * 64 + rr;
      const float* e = ep + rr * 84 + grp * 5;
      float v0 = e[0], v1 = e[1], v2 = e[2], v3 = e[3], v4 = e[4];
      float mx = fmaxf(fmaxf(fmaxf(v0, v1), fmaxf(v2, v3)), v4);
      float ssum = expf(v0 - mx) + expf(v1 - mx) + expf(v2 - mx) +
                   expf(v3 - mx) + expf(v4 - mx);
      float lse = mx + logf(ssum);
      if (row < 16352) {
        float* o = out + (size_t)row * 640 + nblk * 80 + grp * 5;
        o[0] = v0 - lse; o[1] = v1 - lse; o[2] = v2 - lse;
        o[3] = v3 - lse; o[4] = v4 - lse;
      }
    }
  }
}

// ---------------------------------------------------------------------------
__global__ __launch_bounds__(256) void donep_k(
    const u64* __restrict__ hs2, const unsigned short* __restrict__ wout,
    const float* __restrict__ b_out, float* __restrict__ out) {
  const int lane = threadIdx.x & 63;
  const int wv = (blockIdx.x * 256 + threadIdx.x) >> 6;  // 2048 waves
  const unsigned short* wrow = wout + (size_t)1920 * 1024 + lane * 16;
  float wl[16];
#pragma unroll
  for (int i = 0; i < 16; ++i) wl[i] = b2f(wrow[i]);
  const float bias = b_out[1920];
  for (int r = wv; r < 16352; r += 2048) {
    float d = 0.f;
#pragma unroll
    for (int j = 0; j < 4; ++j) {   // k = lane*16 + 4j + (0..3)
      union { u64 q; unsigned short h[4]; } u;
      u.q = hs2[(size_t)(lane * 4 + j) * 16384 + r];
#pragma unroll
      for (int i = 0; i < 4; ++i) d += b2f(u.h[i]) * wl[j * 4 + i];
    }
#pragma unroll
    for (int off = 32; off; off >>= 1) d += __shfl_down(d, off, 64);
    if (lane == 0) out[31395840 + r] = d + bias;
  }
}

// ---------------------------------------------------------------------------
extern "C" void kernel_launch(void* const* d_in, const int* in_sizes, int n_in,
                              void* d_out, int out_size, void* d_ws, size_t ws_size,
                              hipStream_t stream) {
  const float* z       = (const float*)d_in[0];
  const int*   actions = (const int*)d_in[1];
  const int*   dones   = (const int*)d_in[2];
  const float* embed   = (const float*)d_in[3];
  const float* Wih     = (const float*)d_in[4];
  const float* Whh     = (const float*)d_in[5];
  const float* bih     = (const float*)d_in[6];
  const float* bhh     = (const float*)d_in[7];
  const float* Wout    = (const float*)d_in[8];
  const float* bout    = (const float*)d_in[9];
  float* out = (float*)d_out;

  if (ws_size < WS_END) return;  // fail visibly rather than corrupt memory

  char* ws = (char*)d_ws;
  unsigned* gcnt         = (unsigned*)(ws);
  u64* h64               = (u64*)(ws + WS_HBUF);
  unsigned short* zt     = (unsigned short*)(ws + WS_ZT);
  unsigned short* wout16 = (unsigned short*)(ws + WS_WOUT);
  u64* hs2               = (u64*)(ws + WS_HS2);

  // zero barrier counters + initial h (h0 = 0); must happen every launch
  hipMemsetAsync(d_ws, 0, 133120, stream);

  cvt_wout_k<<<1921, 256, 0, stream>>>(Wout, wout16);
  cvt_z_k<<<2048, 256, 0, stream>>>(z, zt);
  zero_hs_tail_k<<<32, 256, 0, stream>>>(hs2);
  lstm_k<<<256, 256, 0, stream>>>(Whh, Wih, embed, bih, bhh, actions, dones,
                                  zt, h64, hs2, gcnt);
  out_gemm_k<<<dim3(256, 24), 256, 0, stream>>>(hs2, wout16, bout, out);
  donep_k<<<512, 256, 0, stream>>>(hs2, wout16, bout, out);
}